// Round 1
// baseline (144.641 us; speedup 1.0000x reference)
//
#include <hip/hip_runtime.h>
#include <math.h>

#define NREL  32
#define NENT  2048
#define NATTR 8
#define WIDTH 256
#define NK    (2 * NREL + NATTR)   // 72

// ---------------------------------------------------------------------------
// Kernel A: one pass over database. Each block = (relation r, row-chunk c).
// 4 waves/block; each wave owns rowsPerWave full rows:
//   - row sum (axis=2) completed in-wave -> write quantified[32+r][i] directly
//   - column partial sums (axis=1) kept in 8 float4 regs/lane, combined
//     across the 4 waves via LDS, one partial row per block -> workspace.
// ---------------------------------------------------------------------------
__global__ __launch_bounds__(256) void reduce_db_kernel(
    const float* __restrict__ db,
    float* __restrict__ qout,        // quantified region [72][2048]
    float* __restrict__ partial,     // [NREL*chunks][2048]
    int chunks, int rowsPerWave)
{
    const int bx    = blockIdx.x;
    const int r     = bx / chunks;
    const int chunk = bx % chunks;
    const int tid   = threadIdx.x;
    const int wave  = tid >> 6;
    const int lane  = tid & 63;

    const int i0 = (chunk * 4 + wave) * rowsPerWave;

    const float4* base =
        reinterpret_cast<const float4*>(db) + (size_t)r * NENT * (NENT / 4);

    float4 acc[8];
#pragma unroll
    for (int k = 0; k < 8; ++k) acc[k] = make_float4(0.f, 0.f, 0.f, 0.f);

    for (int j = 0; j < rowsPerWave; ++j) {
        const int i = i0 + j;
        const float4* row = base + (size_t)i * (NENT / 4);
        float rs = 0.f;
#pragma unroll
        for (int k = 0; k < 8; ++k) {
            float4 v = row[k * 64 + lane];
            acc[k].x += v.x; acc[k].y += v.y;
            acc[k].z += v.z; acc[k].w += v.w;
            rs += (v.x + v.y) + (v.z + v.w);
        }
        // wave-64 butterfly reduce for the row sum
#pragma unroll
        for (int off = 32; off > 0; off >>= 1)
            rs += __shfl_xor(rs, off, 64);
        if (lane == 0)
            qout[(size_t)(NREL + r) * NENT + i] = 1.f - __expf(-rs);
    }

    // combine the 4 waves' column partials via LDS (conflict-free float4)
    __shared__ __align__(16) float lds[4][NENT];
#pragma unroll
    for (int k = 0; k < 8; ++k)
        *reinterpret_cast<float4*>(&lds[wave][k * 256 + lane * 4]) = acc[k];
    __syncthreads();

    float4* part4 = reinterpret_cast<float4*>(partial) + (size_t)bx * (NENT / 4);
    for (int g = tid; g < NENT / 4; g += 256) {
        float4 a0 = *reinterpret_cast<const float4*>(&lds[0][g * 4]);
        float4 a1 = *reinterpret_cast<const float4*>(&lds[1][g * 4]);
        float4 a2 = *reinterpret_cast<const float4*>(&lds[2][g * 4]);
        float4 a3 = *reinterpret_cast<const float4*>(&lds[3][g * 4]);
        float4 s;
        s.x = (a0.x + a1.x) + (a2.x + a3.x);
        s.y = (a0.y + a1.y) + (a2.y + a3.y);
        s.z = (a0.z + a1.z) + (a2.z + a3.z);
        s.w = (a0.w + a1.w) + (a2.w + a3.w);
        part4[g] = s;
    }
}

// ---------------------------------------------------------------------------
// Kernel B: finalize column sums (reduce partials over chunks) + attributes.
// Covers rows 0..31 (axis=1 sums) and attr rows 64..71 of quantified.
// ---------------------------------------------------------------------------
__global__ __launch_bounds__(256) void finalize_kernel(
    const float* __restrict__ partial,
    const float* __restrict__ attrs,
    float* __restrict__ qout,
    int chunks)
{
    const int idx = blockIdx.x * 256 + threadIdx.x;  // over (32+8)*2048
    const int row = idx >> 11;
    const int n   = idx & (NENT - 1);
    if (row < NREL) {
        float s = 0.f;
        for (int c = 0; c < chunks; ++c)
            s += partial[((size_t)(row * chunks + c) << 11) + n];
        qout[((size_t)row << 11) + n] = 1.f - __expf(-s);
    } else {
        const int a = row - NREL;
        float v = attrs[((size_t)a << 11) + n];
        qout[((size_t)(2 * NREL + a) << 11) + n] = 1.f - __expf(-2.f * v);
    }
}

// ---------------------------------------------------------------------------
// Kernel C: softmax over the 72 rows of weights, per output column w.
// ---------------------------------------------------------------------------
__global__ void softmax_kernel(const float* __restrict__ W,
                               float* __restrict__ sw)
{
    const int w = threadIdx.x;  // 0..255
    float m = -INFINITY;
    for (int k = 0; k < NK; ++k) m = fmaxf(m, W[k * WIDTH + w]);
    float s = 0.f;
    for (int k = 0; k < NK; ++k) s += __expf(W[k * WIDTH + w] - m);
    const float inv = 1.f / s;
    for (int k = 0; k < NK; ++k)
        sw[k * WIDTH + w] = __expf(W[k * WIDTH + w] - m) * inv;
}

// ---------------------------------------------------------------------------
// Kernel D: outputs[w][n] = sum_k sw[k][w] * quantified[k][n].
// One block per w: sw loads are wave-uniform (scalar); quantified is
// L2-resident; float4-coalesced stores.
// ---------------------------------------------------------------------------
__global__ __launch_bounds__(256) void matmul_kernel(
    const float* __restrict__ sw,
    const float* __restrict__ quant,
    float* __restrict__ out)
{
    const int w = blockIdx.x;   // 0..255
    const int t = threadIdx.x;  // 0..255, 8 n's each
    const float4* q4 = reinterpret_cast<const float4*>(quant);
    const int g = t * 2;
    float4 a0 = make_float4(0.f, 0.f, 0.f, 0.f);
    float4 a1 = make_float4(0.f, 0.f, 0.f, 0.f);
#pragma unroll 8
    for (int k = 0; k < NK; ++k) {
        const float s = sw[k * WIDTH + w];
        float4 v0 = q4[k * (NENT / 4) + g];
        float4 v1 = q4[k * (NENT / 4) + g + 1];
        a0.x += s * v0.x; a0.y += s * v0.y; a0.z += s * v0.z; a0.w += s * v0.w;
        a1.x += s * v1.x; a1.y += s * v1.y; a1.z += s * v1.z; a1.w += s * v1.w;
    }
    float4* o4 = reinterpret_cast<float4*>(out) + (size_t)w * (NENT / 4);
    o4[g]     = a0;
    o4[g + 1] = a1;
}

extern "C" void kernel_launch(void* const* d_in, const int* in_sizes, int n_in,
                              void* d_out, int out_size, void* d_ws, size_t ws_size,
                              hipStream_t stream)
{
    const float* db    = (const float*)d_in[0];  // [32][2048][2048]
    const float* attrs = (const float*)d_in[1];  // [8][2048]
    const float* W     = (const float*)d_in[2];  // [72][256]

    float* out   = (float*)d_out;                    // [256][2048]
    float* quant = out + (size_t)WIDTH * NENT;       // [72][2048]

    // pick the largest chunk count whose partials (+softmax) fit in d_ws
    int chunks = 16;
    while (chunks > 1 &&
           (size_t)NREL * chunks * NENT * sizeof(float) +
           (size_t)NK * WIDTH * sizeof(float) > ws_size)
        chunks >>= 1;

    float* partial = (float*)d_ws;                         // [32*chunks][2048]
    float* sw      = partial + (size_t)NREL * chunks * NENT; // [72][256]

    const int rowsPerWave = NENT / (chunks * 4);

    reduce_db_kernel<<<NREL * chunks, 256, 0, stream>>>(db, quant, partial,
                                                        chunks, rowsPerWave);
    finalize_kernel<<<(NREL + NATTR) * NENT / 256, 256, 0, stream>>>(
        partial, attrs, quant, chunks);
    softmax_kernel<<<1, WIDTH, 0, stream>>>(W, sw);
    matmul_kernel<<<WIDTH, 256, 0, stream>>>(sw, quant, out);
}

// Round 2
// 124.895 us; speedup vs baseline: 1.1581x; 1.1581x over previous
//
#include <hip/hip_runtime.h>
#include <math.h>

#define NREL  32
#define NENT  2048
#define NATTR 8
#define WIDTH 256
#define NK    (2 * NREL + NATTR)   // 72

// ---------------------------------------------------------------------------
// Kernel A: one pass over database. Each block = (relation r, row-chunk c).
// 4 waves/block; each wave owns rowsPerWave full rows (processed in pairs):
//   - row sums (axis=2) reduced in-wave (paired butterfly) -> quantified[32+r]
//   - column partials (axis=1) in 8 float4 regs/lane, combined across the
//     4 waves via LDS, one partial row per block -> workspace.
// chunks=64 -> 2048 blocks (5 blocks/CU LDS-capped = 20 waves/CU).
// ---------------------------------------------------------------------------
__global__ __launch_bounds__(256) void reduce_db_kernel(
    const float* __restrict__ db,
    float* __restrict__ qout,        // quantified region [72][2048]
    float* __restrict__ partial,     // [NREL*chunks][2048]
    int chunks, int rowsPerWave)
{
    const int bx    = blockIdx.x;
    const int r     = bx / chunks;
    const int chunk = bx % chunks;
    const int tid   = threadIdx.x;
    const int wave  = tid >> 6;
    const int lane  = tid & 63;

    const int i0 = (chunk * 4 + wave) * rowsPerWave;

    const float4* base =
        reinterpret_cast<const float4*>(db) + (size_t)r * NENT * (NENT / 4);

    float4 acc[8];
#pragma unroll
    for (int k = 0; k < 8; ++k) acc[k] = make_float4(0.f, 0.f, 0.f, 0.f);

    for (int j = 0; j < rowsPerWave; j += 2) {
        const float4* rowA = base + (size_t)(i0 + j) * (NENT / 4);
        const float4* rowB = rowA + (NENT / 4);
        float rsA = 0.f, rsB = 0.f;
        // 16 independent float4 loads issued before any cross-lane op
#pragma unroll
        for (int k = 0; k < 8; ++k) {
            float4 v = rowA[k * 64 + lane];
            acc[k].x += v.x; acc[k].y += v.y;
            acc[k].z += v.z; acc[k].w += v.w;
            rsA += (v.x + v.y) + (v.z + v.w);
        }
#pragma unroll
        for (int k = 0; k < 8; ++k) {
            float4 v = rowB[k * 64 + lane];
            acc[k].x += v.x; acc[k].y += v.y;
            acc[k].z += v.z; acc[k].w += v.w;
            rsB += (v.x + v.y) + (v.z + v.w);
        }
        // paired reduction: fold 64->32 for both rows, select, 5-step butterfly
        rsA += __shfl_xor(rsA, 32, 64);
        rsB += __shfl_xor(rsB, 32, 64);
        float c = (lane < 32) ? rsA : rsB;
#pragma unroll
        for (int off = 16; off > 0; off >>= 1)
            c += __shfl_xor(c, off, 64);
        if ((lane & 31) == 0)
            qout[(size_t)(NREL + r) * NENT + i0 + j + (lane >> 5)] =
                1.f - __expf(-c);
    }

    // combine the 4 waves' column partials via LDS (conflict-free float4)
    __shared__ __align__(16) float lds[4][NENT];
#pragma unroll
    for (int k = 0; k < 8; ++k)
        *reinterpret_cast<float4*>(&lds[wave][k * 256 + lane * 4]) = acc[k];
    __syncthreads();

    float4* part4 = reinterpret_cast<float4*>(partial) + (size_t)bx * (NENT / 4);
    for (int g = tid; g < NENT / 4; g += 256) {
        float4 a0 = *reinterpret_cast<const float4*>(&lds[0][g * 4]);
        float4 a1 = *reinterpret_cast<const float4*>(&lds[1][g * 4]);
        float4 a2 = *reinterpret_cast<const float4*>(&lds[2][g * 4]);
        float4 a3 = *reinterpret_cast<const float4*>(&lds[3][g * 4]);
        float4 s;
        s.x = (a0.x + a1.x) + (a2.x + a3.x);
        s.y = (a0.y + a1.y) + (a2.y + a3.y);
        s.z = (a0.z + a1.z) + (a2.z + a3.z);
        s.w = (a0.w + a1.w) + (a2.w + a3.w);
        part4[g] = s;
    }
}

// ---------------------------------------------------------------------------
// Kernel B (merged): blocks 0..319 finalize column sums + attribute rows;
// block 320 does the weights softmax with fully-unrolled independent loads.
// ---------------------------------------------------------------------------
#define FIN_BLOCKS ((NREL + NATTR) * NENT / 256)   // 320

__global__ __launch_bounds__(256) void finalize_softmax_kernel(
    const float* __restrict__ partial,
    const float* __restrict__ attrs,
    const float* __restrict__ W,
    float* __restrict__ qout,
    float* __restrict__ sw,
    int chunks)
{
    const int b = blockIdx.x;
    if (b < FIN_BLOCKS) {
        const int idx = b * 256 + threadIdx.x;   // over (32+8)*2048
        const int row = idx >> 11;
        const int n   = idx & (NENT - 1);
        if (row < NREL) {
            float s = 0.f;
#pragma unroll 4
            for (int c = 0; c < chunks; ++c)
                s += partial[((size_t)(row * chunks + c) << 11) + n];
            qout[((size_t)row << 11) + n] = 1.f - __expf(-s);
        } else {
            const int a = row - NREL;
            float v = attrs[((size_t)a << 11) + n];
            qout[((size_t)(2 * NREL + a) << 11) + n] = 1.f - __expf(-2.f * v);
        }
    } else {
        // softmax over the 72 rows of weights, per output column w
        const int w = threadIdx.x;  // 0..255
        float v[NK];
#pragma unroll
        for (int k = 0; k < NK; ++k) v[k] = W[k * WIDTH + w];  // 72 indep loads
        float m = v[0];
#pragma unroll
        for (int k = 1; k < NK; ++k) m = fmaxf(m, v[k]);
        float s = 0.f;
#pragma unroll
        for (int k = 0; k < NK; ++k) { v[k] = __expf(v[k] - m); s += v[k]; }
        const float inv = 1.f / s;
#pragma unroll
        for (int k = 0; k < NK; ++k) sw[k * WIDTH + w] = v[k] * inv;
    }
}

// ---------------------------------------------------------------------------
// Kernel C: outputs[w][n] = sum_k sw[k][w] * quantified[k][n].
// 2 blocks per w (512 blocks); 1 float4 per thread; sw loads wave-uniform.
// ---------------------------------------------------------------------------
__global__ __launch_bounds__(256) void matmul_kernel(
    const float* __restrict__ sw,
    const float* __restrict__ quant,
    float* __restrict__ out)
{
    const int w    = blockIdx.x >> 1;            // 0..255
    const int g    = (blockIdx.x & 1) * 256 + threadIdx.x;  // float4 col 0..511
    const float4* q4 = reinterpret_cast<const float4*>(quant);
    float4 a = make_float4(0.f, 0.f, 0.f, 0.f);
#pragma unroll 8
    for (int k = 0; k < NK; ++k) {
        const float s = sw[k * WIDTH + w];
        float4 v = q4[k * (NENT / 4) + g];
        a.x += s * v.x; a.y += s * v.y; a.z += s * v.z; a.w += s * v.w;
    }
    reinterpret_cast<float4*>(out)[(size_t)w * (NENT / 4) + g] = a;
}

extern "C" void kernel_launch(void* const* d_in, const int* in_sizes, int n_in,
                              void* d_out, int out_size, void* d_ws, size_t ws_size,
                              hipStream_t stream)
{
    const float* db    = (const float*)d_in[0];  // [32][2048][2048]
    const float* attrs = (const float*)d_in[1];  // [8][2048]
    const float* W     = (const float*)d_in[2];  // [72][256]

    float* out   = (float*)d_out;                    // [256][2048]
    float* quant = out + (size_t)WIDTH * NENT;       // [72][2048]

    // pick the largest chunk count whose partials (+softmax) fit in d_ws
    int chunks = 64;
    while (chunks > 1 &&
           (size_t)NREL * chunks * NENT * sizeof(float) +
           (size_t)NK * WIDTH * sizeof(float) > ws_size)
        chunks >>= 1;

    float* partial = (float*)d_ws;                           // [32*chunks][2048]
    float* sw      = partial + (size_t)NREL * chunks * NENT; // [72][256]

    const int rowsPerWave = NENT / (chunks * 4);             // 8 @ chunks=64

    reduce_db_kernel<<<NREL * chunks, 256, 0, stream>>>(db, quant, partial,
                                                        chunks, rowsPerWave);
    finalize_softmax_kernel<<<FIN_BLOCKS + 1, 256, 0, stream>>>(
        partial, attrs, W, quant, sw, chunks);
    matmul_kernel<<<WIDTH * 2, 256, 0, stream>>>(sw, quant, out);
}